// Round 6
// baseline (180.700 us; speedup 1.0000x reference)
//
#include <hip/hip_runtime.h>

#define BB 64
#define CC 128
#define HH 80
#define WW 80
#define HW 6400
#define SIG2F 0.18f   // 2 * 0.3^2

typedef float f4v __attribute__((ext_vector_type(4)));

__device__ __forceinline__ float dot4(f4v a, f4v b) {
    return a.x * b.x + a.y * b.y + a.z * b.z + a.w * b.w;
}

// half-block (128-thread) sum; node 0 = t<128, node 1 = t>=128 reduce
// independently; result broadcast within each half. All 256 threads call.
__device__ __forceinline__ float halfsum256(float v, int t, float* red4) {
    for (int off = 32; off > 0; off >>= 1) v += __shfl_down(v, off, 64);
    __syncthreads();
    if ((t & 63) == 0) red4[t >> 6] = v;
    __syncthreads();
    int base = (t >> 7) * 2;
    return red4[base] + red4[base + 1];
}

// ---------------------------------------------------------------------------
// K1: fused mask-resize + masked pooling, slab-blocked.
// grid: B*4 blocks (b, slab s of 20 rows), 256 threads (4 waves).
//  - stage m[2][20*80] into LDS from strided masks source
//  - per-slab mask stats partials -> mstat[b][s][n][4] (fsum,cnt,sy,sx)
//  - wave w dots channels [w*32, w*32+32) x-slab against LDS masks
//    -> part[b][s][n][c]
// ---------------------------------------------------------------------------
__global__ __launch_bounds__(256) void poolmask_kernel(
        const float* __restrict__ x, const float* __restrict__ masks,
        float* __restrict__ part, float* __restrict__ mstat) {
    int blk = blockIdx.x;              // b*4 + s
    int b = blk >> 2, s = blk & 3;
    int t = threadIdx.x;
    __shared__ __align__(16) float m[2][1600];
    // ---- stage masks (nearest = stride-8 sample) ----
    for (int p = t; p < 3200; p += 256) {
        int n = p >= 1600;
        int loc = p - n * 1600;
        int y = loc / 80, xx = loc - y * 80;
        int gy = s * 20 + y;
        m[n][loc] = masks[((size_t)(b * 2 + n) * 640 + gy * 8) * 640 + xx * 8];
    }
    __syncthreads();
    // ---- mask stats partials ----
    {
        float fs0 = 0.f, fs1 = 0.f;
        int c0 = 0, c1 = 0, sy0 = 0, sy1 = 0, sx0 = 0, sx1 = 0;
        for (int p = t; p < 1600; p += 256) {
            int y = p / 80, xx = p - y * 80;
            int gy = s * 20 + y;
            float v0 = m[0][p], v1 = m[1][p];
            fs0 += v0; fs1 += v1;
            if (v0 > 0.5f) { c0++; sy0 += gy; sx0 += xx; }
            if (v1 > 0.5f) { c1++; sy1 += gy; sx1 += xx; }
        }
        for (int off = 32; off > 0; off >>= 1) {
            fs0 += __shfl_down(fs0, off, 64); fs1 += __shfl_down(fs1, off, 64);
            c0  += __shfl_down(c0,  off, 64); c1  += __shfl_down(c1,  off, 64);
            sy0 += __shfl_down(sy0, off, 64); sy1 += __shfl_down(sy1, off, 64);
            sx0 += __shfl_down(sx0, off, 64); sx1 += __shfl_down(sx1, off, 64);
        }
        __shared__ float sred[4][8];
        int wave = t >> 6;
        if ((t & 63) == 0) {
            sred[wave][0] = fs0; sred[wave][1] = (float)c0;
            sred[wave][2] = (float)sy0; sred[wave][3] = (float)sx0;
            sred[wave][4] = fs1; sred[wave][5] = (float)c1;
            sred[wave][6] = (float)sy1; sred[wave][7] = (float)sx1;
        }
        __syncthreads();
        if (t < 8) {
            float v = sred[0][t] + sred[1][t] + sred[2][t] + sred[3][t];
            mstat[(((size_t)b * 4 + s) * 2 + (t >> 2)) * 4 + (t & 3)] = v;
        }
    }
    // ---- channel loop: wave-owned channels, m from LDS ----
    int wave = t >> 6, lane = t & 63;
    const f4v* mf0 = (const f4v*)m[0];
    const f4v* mf1 = (const f4v*)m[1];
    #pragma unroll 2
    for (int ci = 0; ci < 32; ci++) {
        int c = wave * 32 + ci;
        const f4v* xp = (const f4v*)x + (size_t)(b * 128 + c) * 1600 + s * 400;
        float d0 = 0.f, d1 = 0.f;
        for (int v = lane; v < 400; v += 64) {
            f4v xv = xp[v];
            d0 += dot4(xv, mf0[v]);
            d1 += dot4(xv, mf1[v]);
        }
        for (int off = 32; off > 0; off >>= 1) {
            d0 += __shfl_down(d0, off, 64);
            d1 += __shfl_down(d1, off, 64);
        }
        if (lane == 0) {
            part[(((size_t)b * 4 + s) * 2 + 0) * 128 + c] = d0;
            part[(((size_t)b * 4 + s) * 2 + 1) * 128 + c] = d1;
        }
    }
}

// ---------------------------------------------------------------------------
// K2: reduce partials -> pos/invms/nodes, then graph attention + FFN + 2x LN.
// grid: B blocks, 256 threads (t<128: node 0, t>=128: node 1).
// ---------------------------------------------------------------------------
__global__ __launch_bounds__(256) void attn2_kernel(
        const float* __restrict__ part, const float* __restrict__ mstat,
        const float* __restrict__ wq, const float* __restrict__ bq,
        const float* __restrict__ wk, const float* __restrict__ bk,
        const float* __restrict__ wv, const float* __restrict__ bv,
        const float* __restrict__ wo, const float* __restrict__ bo,
        const float* __restrict__ g1, const float* __restrict__ be1,
        const float* __restrict__ g2, const float* __restrict__ be2,
        const float* __restrict__ w1, const float* __restrict__ bf1,
        const float* __restrict__ w2, const float* __restrict__ bf2,
        float* __restrict__ h2out, float* __restrict__ pos_out) {
    int b = blockIdx.x, t = threadIdx.x;
    int n = t >> 7, ch = t & 127;
    __shared__ __align__(16) float sn[2][128], sq[2][128], sk[2][128], sv[2][128];
    __shared__ __align__(16) float sao[2][128], sh[2][128], sf[2][256];
    __shared__ float attnw[4][2][2];
    __shared__ float red4[4];
    __shared__ float spos[4];          // px0,py0,px1,py1
    __shared__ float sinv[2];
    if (t < 2) {
        float F = 0.f, C = 0.f, SY = 0.f, SX = 0.f;
        for (int s = 0; s < 4; s++) {
            const float* q = mstat + (((size_t)b * 4 + s) * 2 + t) * 4;
            F += q[0]; C += q[1]; SY += q[2]; SX += q[3];
        }
        spos[t * 2 + 0] = (SX / C) * (2.f / (float)WW) - 1.f;
        spos[t * 2 + 1] = (SY / C) * (2.f / (float)HH) - 1.f;
        sinv[t] = 1.f / (F + 1e-6f);
    }
    __syncthreads();
    float nv = 0.f;
    #pragma unroll
    for (int s = 0; s < 4; s++)
        nv += part[(((size_t)b * 4 + s) * 2 + n) * 128 + ch];
    nv *= sinv[n];
    sn[n][ch] = nv;
    __syncthreads();
    // QKV projections
    {
        float q = bq[ch], k = bk[ch], v = bv[ch];
        const f4v* wq4 = (const f4v*)(wq + (size_t)ch * 128);
        const f4v* wk4 = (const f4v*)(wk + (size_t)ch * 128);
        const f4v* wv4 = (const f4v*)(wv + (size_t)ch * 128);
        const f4v* snn = (const f4v*)sn[n];
        #pragma unroll 4
        for (int c4 = 0; c4 < 32; c4++) {
            f4v a = snn[c4];
            q += dot4(wq4[c4], a);
            k += dot4(wk4[c4], a);
            v += dot4(wv4[c4], a);
        }
        sq[n][ch] = q; sk[n][ch] = k; sv[n][ch] = v;
    }
    __syncthreads();
    // scores + softmax (t < 128): head h = t>>5, dim d = t&31
    if (t < 128) {
        float q0 = sq[0][t], q1 = sq[1][t], k0 = sk[0][t], k1 = sk[1][t];
        float s00 = q0 * k0, s01 = q0 * k1, s10 = q1 * k0, s11 = q1 * k1;
        for (int off = 16; off > 0; off >>= 1) {
            s00 += __shfl_down(s00, off, 32);
            s01 += __shfl_down(s01, off, 32);
            s10 += __shfl_down(s10, off, 32);
            s11 += __shfl_down(s11, off, 32);
        }
        if ((t & 31) == 0) {
            int h = t >> 5;
            const float sc = 0.17677669529663687f;     // 1/sqrt(32)
            float dxp = spos[0] - spos[2];
            float dyp = spos[1] - spos[3];
            float D = sqrtf(dxp * dxp + dyp * dyp);
            float l0 = s00 * sc, l1 = s01 * sc - D;
            float mx = fmaxf(l0, l1);
            float e0 = __expf(l0 - mx), e1 = __expf(l1 - mx);
            float inv = 1.f / (e0 + e1);
            attnw[h][0][0] = e0 * inv; attnw[h][0][1] = e1 * inv;
            l0 = s10 * sc - D; l1 = s11 * sc;
            mx = fmaxf(l0, l1);
            e0 = __expf(l0 - mx); e1 = __expf(l1 - mx);
            inv = 1.f / (e0 + e1);
            attnw[h][1][0] = e0 * inv; attnw[h][1][1] = e1 * inv;
        }
    }
    __syncthreads();
    // attention-weighted V
    {
        int hh = ch >> 5;
        sao[n][ch] = attnw[hh][n][0] * sv[0][ch] + attnw[hh][n][1] * sv[1][ch];
    }
    __syncthreads();
    // out projection + residual
    float r;
    {
        float o = bo[ch];
        const f4v* wo4 = (const f4v*)(wo + (size_t)ch * 128);
        const f4v* saon = (const f4v*)sao[n];
        #pragma unroll 4
        for (int c4 = 0; c4 < 32; c4++) o += dot4(wo4[c4], saon[c4]);
        r = nv + o;
    }
    // LN1
    float mu = halfsum256(r, t, red4) * (1.f / 128.f);
    float d = r - mu;
    float var = halfsum256(d * d, t, red4) * (1.f / 128.f);
    float h = d * rsqrtf(var + 1e-5f) * g1[ch] + be1[ch];
    sh[n][ch] = h;
    __syncthreads();
    // FFN layer 1: thread t owns output j=t for BOTH nodes
    {
        float a0 = bf1[t], a1 = bf1[t];
        const f4v* w14 = (const f4v*)(w1 + (size_t)t * 128);
        const f4v* sh0 = (const f4v*)sh[0];
        const f4v* sh1 = (const f4v*)sh[1];
        #pragma unroll 4
        for (int c4 = 0; c4 < 32; c4++) {
            f4v w = w14[c4];
            a0 += dot4(w, sh0[c4]);
            a1 += dot4(w, sh1[c4]);
        }
        sf[0][t] = fmaxf(a0, 0.f);
        sf[1][t] = fmaxf(a1, 0.f);
    }
    __syncthreads();
    // FFN layer 2 + residual
    float r2;
    {
        float a = bf2[ch];
        const f4v* w24 = (const f4v*)(w2 + (size_t)ch * 256);
        const f4v* sfn = (const f4v*)sf[n];
        #pragma unroll 4
        for (int j4 = 0; j4 < 64; j4++) a += dot4(w24[j4], sfn[j4]);
        r2 = h + a;
    }
    // LN2
    float m2 = halfsum256(r2, t, red4) * (1.f / 128.f);
    float e = r2 - m2;
    float v2 = halfsum256(e * e, t, red4) * (1.f / 128.f);
    h2out[(size_t)(b * 2 + n) * 128 + ch] = e * rsqrtf(v2 + 1e-5f) * g2[ch] + be2[ch];
    if (t < 4) pos_out[b * 4 + t] = spos[t];
}

// ---------------------------------------------------------------------------
// K3: separable gaussian splat + residual add, 4 channels per block.
// out[b,c,y,x] = x[b,c,y,x] + sum_n h2[b,n,c] * wy[n][y] * wx[n][x]
// grid: B*32 blocks, 320 threads; NT stores keep x L3-resident.
// ---------------------------------------------------------------------------
__global__ __launch_bounds__(320) void splat_kernel(const float* __restrict__ x,
                                                    const float* __restrict__ h2,
                                                    const float* __restrict__ pos,
                                                    float* __restrict__ out) {
    int blk = blockIdx.x;              // b*32 + cg
    int b = blk >> 5, cg = blk & 31;
    int tid = threadIdx.x;
    __shared__ __align__(16) float wys[2][HH], wxs[2][WW];
    if (tid < HH) {
        float g = -1.f + (2.f / 79.f) * (float)tid;   // linspace(-1,1,80)
        float px0 = pos[b * 4 + 0], py0 = pos[b * 4 + 1];
        float px1 = pos[b * 4 + 2], py1 = pos[b * 4 + 3];
        float d;
        d = g - py0; wys[0][tid] = __expf(-(d * d) * (1.f / SIG2F));
        d = g - py1; wys[1][tid] = __expf(-(d * d) * (1.f / SIG2F));
        d = g - px0; wxs[0][tid] = __expf(-(d * d) * (1.f / SIG2F));
        d = g - px1; wxs[1][tid] = __expf(-(d * d) * (1.f / SIG2F));
    }
    float h0[4], h1[4];
    #pragma unroll
    for (int c4 = 0; c4 < 4; c4++) {
        h0[c4] = h2[(size_t)(b * 2 + 0) * 128 + cg * 4 + c4];
        h1[c4] = h2[(size_t)(b * 2 + 1) * 128 + cg * 4 + c4];
    }
    __syncthreads();
    int col = tid % 20, y0 = tid / 20;     // y0 in [0,16)
    f4v wx0 = ((const f4v*)wxs[0])[col];
    f4v wx1 = ((const f4v*)wxs[1])[col];
    #pragma unroll
    for (int c4 = 0; c4 < 4; c4++) {
        const f4v* xp = (const f4v*)x + (size_t)(b * 128 + cg * 4 + c4) * 1600;
        f4v* op = (f4v*)out + (size_t)(b * 128 + cg * 4 + c4) * 1600;
        #pragma unroll
        for (int kk = 0; kk < 5; kk++) {
            int y = y0 + kk * 16;
            float a0 = h0[c4] * wys[0][y], a1 = h1[c4] * wys[1][y];
            int idx = y * 20 + col;        // == tid + kk*320, coalesced
            f4v xv = xp[idx];
            f4v o = xv + a0 * wx0 + a1 * wx1;
            __builtin_nontemporal_store(o, op + idx);
        }
    }
}

// ---------------------------------------------------------------------------
extern "C" void kernel_launch(void* const* d_in, const int* in_sizes, int n_in,
                              void* d_out, int out_size, void* d_ws, size_t ws_size,
                              hipStream_t stream) {
    const float* x     = (const float*)d_in[0];
    const float* masks = (const float*)d_in[1];
    const float* wq = (const float*)d_in[2],  *bq = (const float*)d_in[3];
    const float* wk = (const float*)d_in[4],  *bk = (const float*)d_in[5];
    const float* wv = (const float*)d_in[6],  *bv = (const float*)d_in[7];
    const float* wo = (const float*)d_in[8],  *bo = (const float*)d_in[9];
    const float* g1 = (const float*)d_in[10], *be1 = (const float*)d_in[11];
    const float* g2 = (const float*)d_in[12], *be2 = (const float*)d_in[13];
    const float* w1 = (const float*)d_in[14], *bf1 = (const float*)d_in[15];
    const float* w2 = (const float*)d_in[16], *bf2 = (const float*)d_in[17];
    float* out = (float*)d_out;

    // workspace layout (floats)
    float* ws    = (float*)d_ws;
    float* part  = ws;                 // 64*4*2*128 = 65536
    float* mstat = ws + 65536;         // 64*4*2*4   = 2048
    float* h2    = ws + 67584;         // 16384
    float* pos   = ws + 83968;         // 256

    poolmask_kernel<<<BB * 4, 256, 0, stream>>>(x, masks, part, mstat);
    attn2_kernel<<<BB, 256, 0, stream>>>(part, mstat,
                                         wq, bq, wk, bk, wv, bv, wo, bo,
                                         g1, be1, g2, be2, w1, bf1, w2, bf2,
                                         h2, pos);
    splat_kernel<<<BB * 32, 320, 0, stream>>>(x, h2, pos, out);
}

// Round 7
// 138.387 us; speedup vs baseline: 1.3058x; 1.3058x over previous
//
#include <hip/hip_runtime.h>

#define BB 64
#define CC 128
#define HH 80
#define WW 80
#define HW 6400
#define SIG2F 0.18f   // 2 * 0.3^2

typedef float f4v __attribute__((ext_vector_type(4)));

__device__ __forceinline__ float dot4(f4v a, f4v b) {
    return a.x * b.x + a.y * b.y + a.z * b.z + a.w * b.w;
}

// half-block (128-thread) sum; node 0 = t<128, node 1 = t>=128 reduce
// independently; result broadcast within each half. All 256 threads call.
__device__ __forceinline__ float halfsum256(float v, int t, float* red4) {
    for (int off = 32; off > 0; off >>= 1) v += __shfl_down(v, off, 64);
    __syncthreads();
    if ((t & 63) == 0) red4[t >> 6] = v;
    __syncthreads();
    int base = (t >> 7) * 2;
    return red4[base] + red4[base + 1];
}

// ---------------------------------------------------------------------------
// Kernel A: nearest-resize masks (640->80 = stride-8 sample), store float mask,
// binary centroid -> pos, 1/(float-mask-sum + 1e-6). 128 blocks x 1024 thr.
// ---------------------------------------------------------------------------
__global__ __launch_bounds__(1024) void mask_kernel(const float* __restrict__ masks,
                                                    float* __restrict__ m_res,
                                                    float* __restrict__ pos,
                                                    float* __restrict__ invms) {
    int plane = blockIdx.x;            // b*2 + n
    int tid = threadIdx.x;
    const float* mp = masks + (size_t)plane * 640 * 640;
    float* mo = m_res + (size_t)plane * HW;
    float fsum = 0.f; int cnt = 0, sy = 0, sx = 0;
    for (int p = tid; p < HW; p += 1024) {
        int y = p / WW, x = p - y * WW;
        float v = mp[(size_t)(y * 8) * 640 + x * 8];
        mo[p] = v;
        fsum += v;
        if (v > 0.5f) { cnt++; sy += y; sx += x; }
    }
    for (int off = 32; off > 0; off >>= 1) {
        fsum += __shfl_down(fsum, off, 64);
        cnt  += __shfl_down(cnt,  off, 64);
        sy   += __shfl_down(sy,   off, 64);
        sx   += __shfl_down(sx,   off, 64);
    }
    __shared__ float rf[16];
    __shared__ int rc[16], ry[16], rx[16];
    int wid = tid >> 6;
    if ((tid & 63) == 0) { rf[wid] = fsum; rc[wid] = cnt; ry[wid] = sy; rx[wid] = sx; }
    __syncthreads();
    if (tid == 0) {
        float F = 0.f; int C = 0, Y = 0, X = 0;
        for (int i = 0; i < 16; i++) { F += rf[i]; C += rc[i]; Y += ry[i]; X += rx[i]; }
        float c = (float)C;
        pos[plane * 2 + 0] = ((float)X / c) / (float)WW * 2.f - 1.f;
        pos[plane * 2 + 1] = ((float)Y / c) / (float)HH * 2.f - 1.f;
        invms[plane] = 1.f / (F + 1e-6f);
    }
}

// ---------------------------------------------------------------------------
// Kernel B: masked average pooling, 4 channels per block.
// nodes[b,n,c] = dot(x[b,c,:,:], m[b,n,:,:]) * invms
// grid: B*32 blocks (8/CU, 32 waves/CU), 256 threads. Each m float4 pair
// feeds 4 x-streams from registers: m_res L2 traffic cut 4x vs 1ch/block.
// ---------------------------------------------------------------------------
__global__ __launch_bounds__(256) void pool_kernel(const float* __restrict__ x,
                                                   const float* __restrict__ m_res,
                                                   const float* __restrict__ invms,
                                                   float* __restrict__ nodes) {
    int blk = blockIdx.x;              // b*32 + cg
    int b = blk >> 5, cg = blk & 31;
    int tid = threadIdx.x;
    const f4v* m0  = (const f4v*)(m_res + (size_t)(b * 2 + 0) * HW);
    const f4v* m1  = (const f4v*)(m_res + (size_t)(b * 2 + 1) * HW);
    const f4v* xp0 = (const f4v*)(x + (size_t)(b * 128 + cg * 4 + 0) * HW);
    const f4v* xp1 = (const f4v*)(x + (size_t)(b * 128 + cg * 4 + 1) * HW);
    const f4v* xp2 = (const f4v*)(x + (size_t)(b * 128 + cg * 4 + 2) * HW);
    const f4v* xp3 = (const f4v*)(x + (size_t)(b * 128 + cg * 4 + 3) * HW);
    float s[8];
    #pragma unroll
    for (int i = 0; i < 8; i++) s[i] = 0.f;
    for (int v = tid; v < HW / 4; v += 256) {
        f4v a = m0[v], bb = m1[v];
        f4v x0 = xp0[v], x1 = xp1[v], x2 = xp2[v], x3 = xp3[v];
        s[0] += dot4(x0, a); s[1] += dot4(x0, bb);
        s[2] += dot4(x1, a); s[3] += dot4(x1, bb);
        s[4] += dot4(x2, a); s[5] += dot4(x2, bb);
        s[6] += dot4(x3, a); s[7] += dot4(x3, bb);
    }
    for (int off = 32; off > 0; off >>= 1) {
        #pragma unroll
        for (int i = 0; i < 8; i++) s[i] += __shfl_down(s[i], off, 64);
    }
    __shared__ float r[4][8];
    int wid = tid >> 6;
    if ((tid & 63) == 0) {
        #pragma unroll
        for (int i = 0; i < 8; i++) r[wid][i] = s[i];
    }
    __syncthreads();
    if (tid < 8) {
        float t = r[0][tid] + r[1][tid] + r[2][tid] + r[3][tid];
        int c4 = tid >> 1, n = tid & 1;
        nodes[(size_t)(b * 2 + n) * 128 + cg * 4 + c4] = t * invms[b * 2 + n];
    }
}

// ---------------------------------------------------------------------------
// Kernel C: graph attention (N=2, 4 heads x 32) + out-proj + LN + FFN + LN.
// grid: B blocks, 256 threads (t<128: node 0, t>=128: node 1), float4 weights.
// ---------------------------------------------------------------------------
__global__ __launch_bounds__(256) void attn_kernel(
        const float* __restrict__ nodes, const float* __restrict__ pos,
        const float* __restrict__ wq, const float* __restrict__ bq,
        const float* __restrict__ wk, const float* __restrict__ bk,
        const float* __restrict__ wv, const float* __restrict__ bv,
        const float* __restrict__ wo, const float* __restrict__ bo,
        const float* __restrict__ g1, const float* __restrict__ be1,
        const float* __restrict__ g2, const float* __restrict__ be2,
        const float* __restrict__ w1, const float* __restrict__ bf1,
        const float* __restrict__ w2, const float* __restrict__ bf2,
        float* __restrict__ h2out) {
    int b = blockIdx.x, t = threadIdx.x;
    int n = t >> 7, ch = t & 127;
    __shared__ __align__(16) float sn[2][128], sq[2][128], sk[2][128], sv[2][128];
    __shared__ __align__(16) float sao[2][128], sh[2][128], sf[2][256];
    __shared__ float attnw[4][2][2];
    __shared__ float red4[4];
    float nv = nodes[(size_t)(b * 2 + n) * 128 + ch];
    sn[n][ch] = nv;
    __syncthreads();
    // QKV projections: thread (n, ch), float4 weight rows
    {
        float q = bq[ch], k = bk[ch], v = bv[ch];
        const f4v* wq4 = (const f4v*)(wq + (size_t)ch * 128);
        const f4v* wk4 = (const f4v*)(wk + (size_t)ch * 128);
        const f4v* wv4 = (const f4v*)(wv + (size_t)ch * 128);
        const f4v* snn = (const f4v*)sn[n];
        #pragma unroll 4
        for (int c4 = 0; c4 < 32; c4++) {
            f4v a = snn[c4];
            q += dot4(wq4[c4], a);
            k += dot4(wk4[c4], a);
            v += dot4(wv4[c4], a);
        }
        sq[n][ch] = q; sk[n][ch] = k; sv[n][ch] = v;
    }
    __syncthreads();
    // scores + softmax (t < 128): head h = t>>5, dim d = t&31
    if (t < 128) {
        float q0 = sq[0][t], q1 = sq[1][t], k0 = sk[0][t], k1 = sk[1][t];
        float s00 = q0 * k0, s01 = q0 * k1, s10 = q1 * k0, s11 = q1 * k1;
        for (int off = 16; off > 0; off >>= 1) {
            s00 += __shfl_down(s00, off, 32);
            s01 += __shfl_down(s01, off, 32);
            s10 += __shfl_down(s10, off, 32);
            s11 += __shfl_down(s11, off, 32);
        }
        if ((t & 31) == 0) {
            int h = t >> 5;
            const float sc = 0.17677669529663687f;     // 1/sqrt(32)
            float dxp = pos[b * 4 + 0] - pos[b * 4 + 2];
            float dyp = pos[b * 4 + 1] - pos[b * 4 + 3];
            float D = sqrtf(dxp * dxp + dyp * dyp);
            float l0 = s00 * sc, l1 = s01 * sc - D;
            float mx = fmaxf(l0, l1);
            float e0 = __expf(l0 - mx), e1 = __expf(l1 - mx);
            float inv = 1.f / (e0 + e1);
            attnw[h][0][0] = e0 * inv; attnw[h][0][1] = e1 * inv;
            l0 = s10 * sc - D; l1 = s11 * sc;
            mx = fmaxf(l0, l1);
            e0 = __expf(l0 - mx); e1 = __expf(l1 - mx);
            inv = 1.f / (e0 + e1);
            attnw[h][1][0] = e0 * inv; attnw[h][1][1] = e1 * inv;
        }
    }
    __syncthreads();
    // attention-weighted V
    {
        int hh = ch >> 5;
        sao[n][ch] = attnw[hh][n][0] * sv[0][ch] + attnw[hh][n][1] * sv[1][ch];
    }
    __syncthreads();
    // out projection + residual
    float r;
    {
        float o = bo[ch];
        const f4v* wo4 = (const f4v*)(wo + (size_t)ch * 128);
        const f4v* saon = (const f4v*)sao[n];
        #pragma unroll 4
        for (int c4 = 0; c4 < 32; c4++) o += dot4(wo4[c4], saon[c4]);
        r = nv + o;
    }
    // LN1
    float mu = halfsum256(r, t, red4) * (1.f / 128.f);
    float d = r - mu;
    float var = halfsum256(d * d, t, red4) * (1.f / 128.f);
    float h = d * rsqrtf(var + 1e-5f) * g1[ch] + be1[ch];
    sh[n][ch] = h;
    __syncthreads();
    // FFN layer 1: thread t owns output j=t for BOTH nodes (weight row reuse)
    {
        float a0 = bf1[t], a1 = bf1[t];
        const f4v* w14 = (const f4v*)(w1 + (size_t)t * 128);
        const f4v* sh0 = (const f4v*)sh[0];
        const f4v* sh1 = (const f4v*)sh[1];
        #pragma unroll 4
        for (int c4 = 0; c4 < 32; c4++) {
            f4v w = w14[c4];
            a0 += dot4(w, sh0[c4]);
            a1 += dot4(w, sh1[c4]);
        }
        sf[0][t] = fmaxf(a0, 0.f);
        sf[1][t] = fmaxf(a1, 0.f);
    }
    __syncthreads();
    // FFN layer 2 + residual
    float r2;
    {
        float a = bf2[ch];
        const f4v* w24 = (const f4v*)(w2 + (size_t)ch * 256);
        const f4v* sfn = (const f4v*)sf[n];
        #pragma unroll 4
        for (int j4 = 0; j4 < 64; j4++) a += dot4(w24[j4], sfn[j4]);
        r2 = h + a;
    }
    // LN2
    float m2 = halfsum256(r2, t, red4) * (1.f / 128.f);
    float e = r2 - m2;
    float v2 = halfsum256(e * e, t, red4) * (1.f / 128.f);
    h2out[(size_t)(b * 2 + n) * 128 + ch] = e * rsqrtf(v2 + 1e-5f) * g2[ch] + be2[ch];
}

// ---------------------------------------------------------------------------
// Kernel D: separable gaussian splat + residual add.
// out[b,c,y,x] = x[b,c,y,x] + sum_n h2[b,n,c] * wy[n][y] * wx[n][x]
// 320 threads: thread tid covers idx = tid + 320k (coalesced); wx in registers.
// NT stores keep x L3-resident.
// ---------------------------------------------------------------------------
__global__ __launch_bounds__(320) void splat_kernel(const float* __restrict__ x,
                                                    const float* __restrict__ h2,
                                                    const float* __restrict__ pos,
                                                    float* __restrict__ out) {
    int blk = blockIdx.x;              // b*128 + c
    int b = blk >> 7, c = blk & 127;
    int tid = threadIdx.x;
    __shared__ __align__(16) float wys[2][HH], wxs[2][WW];
    if (tid < HH) {
        float g = -1.f + (2.f / 79.f) * (float)tid;   // linspace(-1,1,80)
        float px0 = pos[b * 4 + 0], py0 = pos[b * 4 + 1];
        float px1 = pos[b * 4 + 2], py1 = pos[b * 4 + 3];
        float d;
        d = g - py0; wys[0][tid] = __expf(-(d * d) * (1.f / SIG2F));
        d = g - py1; wys[1][tid] = __expf(-(d * d) * (1.f / SIG2F));
        d = g - px0; wxs[0][tid] = __expf(-(d * d) * (1.f / SIG2F));
        d = g - px1; wxs[1][tid] = __expf(-(d * d) * (1.f / SIG2F));
    }
    float h0 = h2[(size_t)(b * 2 + 0) * 128 + c];
    float h1 = h2[(size_t)(b * 2 + 1) * 128 + c];
    __syncthreads();
    int gcol = tid % 20, y0 = tid / 20;     // y0 in [0,16)
    f4v wx0 = ((const f4v*)wxs[0])[gcol];
    f4v wx1 = ((const f4v*)wxs[1])[gcol];
    const f4v* xp = (const f4v*)(x + (size_t)blk * HW);
    f4v* op = (f4v*)(out + (size_t)blk * HW);
    #pragma unroll
    for (int kk = 0; kk < 5; kk++) {
        int y = y0 + kk * 16;
        float a0 = h0 * wys[0][y], a1 = h1 * wys[1][y];
        int idx = y * 20 + gcol;            // == tid + kk*320, coalesced
        f4v xv = xp[idx];
        f4v o = xv + a0 * wx0 + a1 * wx1;
        __builtin_nontemporal_store(o, op + idx);
    }
}

// ---------------------------------------------------------------------------
extern "C" void kernel_launch(void* const* d_in, const int* in_sizes, int n_in,
                              void* d_out, int out_size, void* d_ws, size_t ws_size,
                              hipStream_t stream) {
    const float* x     = (const float*)d_in[0];
    const float* masks = (const float*)d_in[1];
    const float* wq = (const float*)d_in[2],  *bq = (const float*)d_in[3];
    const float* wk = (const float*)d_in[4],  *bk = (const float*)d_in[5];
    const float* wv = (const float*)d_in[6],  *bv = (const float*)d_in[7];
    const float* wo = (const float*)d_in[8],  *bo = (const float*)d_in[9];
    const float* g1 = (const float*)d_in[10], *be1 = (const float*)d_in[11];
    const float* g2 = (const float*)d_in[12], *be2 = (const float*)d_in[13];
    const float* w1 = (const float*)d_in[14], *bf1 = (const float*)d_in[15];
    const float* w2 = (const float*)d_in[16], *bf2 = (const float*)d_in[17];
    float* out = (float*)d_out;

    // workspace layout (floats)
    float* ws     = (float*)d_ws;
    float* m_res  = ws;                       // 64*2*6400 = 819200
    float* pos    = ws + 819200;              // 256
    float* invms  = ws + 819456;              // 128
    float* nodes  = ws + 819584;              // 16384
    float* h2     = ws + 835968;              // 16384   (total ~3.4 MB)

    mask_kernel<<<BB * 2, 1024, 0, stream>>>(masks, m_res, pos, invms);
    pool_kernel<<<BB * 32, 256, 0, stream>>>(x, m_res, invms, nodes);
    attn_kernel<<<BB, 256, 0, stream>>>(nodes, pos,
                                        wq, bq, wk, bk, wv, bv, wo, bo,
                                        g1, be1, g2, be2, w1, bf1, w2, bf2, h2);
    splat_kernel<<<BB * CC, 320, 0, stream>>>(x, h2, pos, out);
}